// Round 1
// baseline (962.233 us; speedup 1.0000x reference)
//
#include <hip/hip_runtime.h>
#include <cstdint>
#include <cstddef>

#define T_DIM 4
#define B_DIM 32
#define C_DIM 256
#define N_DIM 1024
#define NHEAD 8
#define DHEAD 32

// LIF step, mirroring reference rounding exactly:
//   v = v + (x - v)/2 ; s = heaviside(v - vth) ; v = v*(1-s) (hard reset)
__device__ __forceinline__ float lif_step(float& v, float x, float vth) {
    v = __fadd_rn(v, __fmul_rn(__fsub_rn(x, v), 0.5f));
    const float s = (v >= vth) ? 1.0f : 0.0f;   // v - vth >= 0 <=> v >= vth (exact)
    if (s != 0.0f) v = 0.0f;
    return s;
}

// K1: fused Q/K GEMM + BN + LIF + head-sum + attn LIF + x_one (binary, u8)
// grid (NHEAD, N/64, B), block 256. Tile: rows 0..31 = q-channels of head h,
// rows 32..63 = k-channels. LIF state lives in registers across the t-loop.
__global__ __launch_bounds__(256) void k_qk(
    const float* __restrict__ x,
    const float* __restrict__ qw, const float* __restrict__ qg,
    const float* __restrict__ qbeta, const float* __restrict__ qmean, const float* __restrict__ qvar,
    const float* __restrict__ kw, const float* __restrict__ kg,
    const float* __restrict__ kbeta, const float* __restrict__ kmean, const float* __restrict__ kvar,
    uint8_t* __restrict__ xone)
{
    __shared__ float w_lds[64 * 64];   // [k][m]
    __shared__ float x_lds[64 * 64];   // [k][n]
    __shared__ float qsum_lds[64];
    __shared__ float attn_lds[64];

    const int tid = threadIdx.x;
    const int h   = blockIdx.x;
    const int nt  = blockIdx.y;
    const int b   = blockIdx.z;
    const int n0g = nt * 64;

    const int  mg   = tid >> 4;        // 0..15 row group (4 rows each)
    const int  m0   = mg << 2;
    const int  n0   = (tid & 15) << 2; // 4 consecutive cols
    const bool is_q = (mg < 8);

    // per-thread BN constants for its 4 rows (bias exactly 0 for this instance,
    // so mul+add ordering vs fma is moot, but keep it explicit)
    float inv4[4], bias4[4];
    {
        const float* g  = is_q ? qg    : kg;
        const float* be = is_q ? qbeta : kbeta;
        const float* me = is_q ? qmean : kmean;
        const float* va = is_q ? qvar  : kvar;
        const int cb = h * DHEAD + (is_q ? m0 : (m0 - 32));
        #pragma unroll
        for (int i = 0; i < 4; i++) {
            const float iv = __fdiv_rn(g[cb + i], __fsqrt_rn(__fadd_rn(va[cb + i], 1e-5f)));
            inv4[i]  = iv;
            bias4[i] = __fsub_rn(be[cb + i], __fmul_rn(me[cb + i], iv));
        }
    }

    // staging assignments
    const int wo  = tid & 63;          // weight output row 0..63
    const int wkq = tid >> 6;          // k quarter 0..3
    const float* wrow = (wo < 32) ? (qw + (size_t)(h * DHEAD + wo) * C_DIM)
                                  : (kw + (size_t)(h * DHEAD + wo - 32) * C_DIM);
    const int xr  = tid >> 2;          // x row (k) 0..63
    const int xcb = (tid & 3) << 4;    // x col base (16 floats per thread)

    float vstate[16];
    #pragma unroll
    for (int i = 0; i < 16; i++) vstate[i] = 0.0f;
    float v_attn = 0.0f;

    for (int t = 0; t < T_DIM; ++t) {
        float acc[16];
        #pragma unroll
        for (int i = 0; i < 16; i++) acc[i] = 0.0f;

        const float* xb = x + ((size_t)(t * B_DIM + b) * C_DIM) * N_DIM + n0g;

        for (int kk = 0; kk < C_DIM; kk += 64) {
            __syncthreads();                       // prior readers done
            if (kk == 0 && tid < 64) qsum_lds[tid] = 0.0f;
            // stage weights, transposed to [k][m]
            #pragma unroll
            for (int j = 0; j < 4; j++) {
                const int k = (wkq << 4) + (j << 2);
                const float4 wv = *(const float4*)(wrow + kk + k);
                w_lds[(k + 0) * 64 + wo] = wv.x;
                w_lds[(k + 1) * 64 + wo] = wv.y;
                w_lds[(k + 2) * 64 + wo] = wv.z;
                w_lds[(k + 3) * 64 + wo] = wv.w;
            }
            // stage x tile [k][n] (straight copy, coalesced)
            #pragma unroll
            for (int j = 0; j < 4; j++) {
                *(float4*)(x_lds + xr * 64 + xcb + (j << 2)) =
                    *(const float4*)(xb + (size_t)(kk + xr) * N_DIM + xcb + (j << 2));
            }
            __syncthreads();
            // inner GEMM: strict k-ascending single accumulator chain
            #pragma unroll 4
            for (int k = 0; k < 64; k++) {
                const float4 a  = *(const float4*)(w_lds + k * 64 + m0);
                const float4 bv = *(const float4*)(x_lds + k * 64 + n0);
                acc[ 0] = fmaf(a.x, bv.x, acc[ 0]);
                acc[ 1] = fmaf(a.x, bv.y, acc[ 1]);
                acc[ 2] = fmaf(a.x, bv.z, acc[ 2]);
                acc[ 3] = fmaf(a.x, bv.w, acc[ 3]);
                acc[ 4] = fmaf(a.y, bv.x, acc[ 4]);
                acc[ 5] = fmaf(a.y, bv.y, acc[ 5]);
                acc[ 6] = fmaf(a.y, bv.z, acc[ 6]);
                acc[ 7] = fmaf(a.y, bv.w, acc[ 7]);
                acc[ 8] = fmaf(a.z, bv.x, acc[ 8]);
                acc[ 9] = fmaf(a.z, bv.y, acc[ 9]);
                acc[10] = fmaf(a.z, bv.z, acc[10]);
                acc[11] = fmaf(a.z, bv.w, acc[11]);
                acc[12] = fmaf(a.w, bv.x, acc[12]);
                acc[13] = fmaf(a.w, bv.y, acc[13]);
                acc[14] = fmaf(a.w, bv.z, acc[14]);
                acc[15] = fmaf(a.w, bv.w, acc[15]);
            }
        }

        // BN + LIF
        float sarr[16];
        #pragma unroll
        for (int i = 0; i < 4; i++) {
            #pragma unroll
            for (int j = 0; j < 4; j++) {
                const float y = __fadd_rn(__fmul_rn(acc[i * 4 + j], inv4[i]), bias4[i]);
                sarr[i * 4 + j] = lif_step(vstate[i * 4 + j], y, 1.0f);
            }
        }

        // head-sum of q spikes (integer-valued -> exact in any order)
        if (is_q) {
            #pragma unroll
            for (int j = 0; j < 4; j++) {
                const float cs = sarr[j] + sarr[4 + j] + sarr[8 + j] + sarr[12 + j];
                atomicAdd(&qsum_lds[n0 + j], cs);
            }
        }
        __syncthreads();
        if (tid < 64) {
            attn_lds[tid] = lif_step(v_attn, qsum_lds[tid], 0.5f);
        }
        __syncthreads();
        // x_one = attn * k_spikes (binary), packed u8, 4 bytes per store
        if (!is_q) {
            #pragma unroll
            for (int i = 0; i < 4; i++) {
                uint32_t pack = 0;
                #pragma unroll
                for (int j = 0; j < 4; j++) {
                    if (sarr[i * 4 + j] != 0.0f && attn_lds[n0 + j] != 0.0f)
                        pack |= (1u << (8 * j));
                }
                const int c = h * DHEAD + (m0 - 32) + i;
                *(uint32_t*)(xone + ((size_t)(t * B_DIM + b) * C_DIM + c) * N_DIM + n0g + n0) = pack;
            }
        }
    }
}

// K2: projection GEMM (u8 binary input) + bias + BN + LIF -> spikes
// grid (C/64, N/64, B), block 256.
__global__ __launch_bounds__(256) void k_proj(
    const uint8_t* __restrict__ xone,
    const float* __restrict__ pw, const float* __restrict__ pbias,
    const float* __restrict__ pg, const float* __restrict__ pbeta,
    const float* __restrict__ pmean, const float* __restrict__ pvar,
    float* __restrict__ out)
{
    __shared__ float w_lds[64 * 64];
    __shared__ float x_lds[64 * 64];

    const int tid = threadIdx.x;
    const int mt  = blockIdx.x;
    const int nt  = blockIdx.y;
    const int b   = blockIdx.z;
    const int n0g = nt * 64;
    const int c0  = mt * 64;

    const int mg = tid >> 4;
    const int m0 = mg << 2;
    const int n0 = (tid & 15) << 2;

    float inv4[4], bias4[4], pb4[4];
    #pragma unroll
    for (int i = 0; i < 4; i++) {
        const int c = c0 + m0 + i;
        const float iv = __fdiv_rn(pg[c], __fsqrt_rn(__fadd_rn(pvar[c], 1e-5f)));
        inv4[i]  = iv;
        bias4[i] = __fsub_rn(pbeta[c], __fmul_rn(pmean[c], iv));
        pb4[i]   = pbias[c];
    }

    const int wo  = tid & 63;
    const int wkq = tid >> 6;
    const float* wrow = pw + (size_t)(c0 + wo) * C_DIM;
    const int xr  = tid >> 2;
    const int xcb = (tid & 3) << 4;

    float vstate[16];
    #pragma unroll
    for (int i = 0; i < 16; i++) vstate[i] = 0.0f;

    for (int t = 0; t < T_DIM; ++t) {
        float acc[16];
        #pragma unroll
        for (int i = 0; i < 16; i++) acc[i] = 0.0f;

        const uint8_t* xb = xone + ((size_t)(t * B_DIM + b) * C_DIM) * N_DIM + n0g;

        for (int kk = 0; kk < C_DIM; kk += 64) {
            __syncthreads();
            #pragma unroll
            for (int j = 0; j < 4; j++) {
                const int k = (wkq << 4) + (j << 2);
                const float4 wv = *(const float4*)(wrow + kk + k);
                w_lds[(k + 0) * 64 + wo] = wv.x;
                w_lds[(k + 1) * 64 + wo] = wv.y;
                w_lds[(k + 2) * 64 + wo] = wv.z;
                w_lds[(k + 3) * 64 + wo] = wv.w;
            }
            {
                const uint4 pv = *(const uint4*)(xb + (size_t)(kk + xr) * N_DIM + xcb);
                const uint32_t u[4] = {pv.x, pv.y, pv.z, pv.w};
                #pragma unroll
                for (int j = 0; j < 4; j++) {
                    float4 f;
                    f.x = (float)( u[j]        & 0xffu);
                    f.y = (float)((u[j] >> 8 ) & 0xffu);
                    f.z = (float)((u[j] >> 16) & 0xffu);
                    f.w = (float)( u[j] >> 24        );
                    *(float4*)(x_lds + xr * 64 + xcb + (j << 2)) = f;
                }
            }
            __syncthreads();
            #pragma unroll 4
            for (int k = 0; k < 64; k++) {
                const float4 a  = *(const float4*)(w_lds + k * 64 + m0);
                const float4 bv = *(const float4*)(x_lds + k * 64 + n0);
                acc[ 0] = fmaf(a.x, bv.x, acc[ 0]);
                acc[ 1] = fmaf(a.x, bv.y, acc[ 1]);
                acc[ 2] = fmaf(a.x, bv.z, acc[ 2]);
                acc[ 3] = fmaf(a.x, bv.w, acc[ 3]);
                acc[ 4] = fmaf(a.y, bv.x, acc[ 4]);
                acc[ 5] = fmaf(a.y, bv.y, acc[ 5]);
                acc[ 6] = fmaf(a.y, bv.z, acc[ 6]);
                acc[ 7] = fmaf(a.y, bv.w, acc[ 7]);
                acc[ 8] = fmaf(a.z, bv.x, acc[ 8]);
                acc[ 9] = fmaf(a.z, bv.y, acc[ 9]);
                acc[10] = fmaf(a.z, bv.z, acc[10]);
                acc[11] = fmaf(a.z, bv.w, acc[11]);
                acc[12] = fmaf(a.w, bv.x, acc[12]);
                acc[13] = fmaf(a.w, bv.y, acc[13]);
                acc[14] = fmaf(a.w, bv.z, acc[14]);
                acc[15] = fmaf(a.w, bv.w, acc[15]);
            }
        }

        #pragma unroll
        for (int i = 0; i < 4; i++) {
            float s4[4];
            #pragma unroll
            for (int j = 0; j < 4; j++) {
                float y = __fadd_rn(acc[i * 4 + j], pb4[i]);
                y = __fadd_rn(__fmul_rn(y, inv4[i]), bias4[i]);
                s4[j] = lif_step(vstate[i * 4 + j], y, 1.0f);
            }
            const int c = c0 + m0 + i;
            float4 o4;
            o4.x = s4[0]; o4.y = s4[1]; o4.z = s4[2]; o4.w = s4[3];
            *(float4*)(out + ((size_t)(t * B_DIM + b) * C_DIM + c) * N_DIM + n0g + n0) = o4;
        }
    }
}

extern "C" void kernel_launch(void* const* d_in, const int* in_sizes, int n_in,
                              void* d_out, int out_size, void* d_ws, size_t ws_size,
                              hipStream_t stream) {
    const float* x     = (const float*)d_in[0];
    const float* q_w   = (const float*)d_in[1];
    const float* q_g   = (const float*)d_in[2];
    const float* q_b   = (const float*)d_in[3];
    const float* q_m   = (const float*)d_in[4];
    const float* q_v   = (const float*)d_in[5];
    const float* k_w   = (const float*)d_in[6];
    const float* k_g   = (const float*)d_in[7];
    const float* k_b   = (const float*)d_in[8];
    const float* k_m   = (const float*)d_in[9];
    const float* k_v   = (const float*)d_in[10];
    const float* p_w   = (const float*)d_in[11];
    const float* p_b   = (const float*)d_in[12];
    const float* p_g   = (const float*)d_in[13];
    const float* p_be  = (const float*)d_in[14];
    const float* p_m   = (const float*)d_in[15];
    const float* p_v   = (const float*)d_in[16];

    uint8_t* x_one = (uint8_t*)d_ws;     // T*B*C*N = 33.5 MB of u8
    float*   out   = (float*)d_out;

    dim3 g1(NHEAD, N_DIM / 64, B_DIM);
    k_qk<<<g1, 256, 0, stream>>>(x, q_w, q_g, q_b, q_m, q_v,
                                 k_w, k_g, k_b, k_m, k_v, x_one);

    dim3 g2(C_DIM / 64, N_DIM / 64, B_DIM);
    k_proj<<<g2, 256, 0, stream>>>(x_one, p_w, p_b, p_g, p_be, p_m, p_v, out);
}

// Round 2
// 907.281 us; speedup vs baseline: 1.0606x; 1.0606x over previous
//
#include <hip/hip_runtime.h>
#include <cstdint>
#include <cstddef>

#define T_DIM 4
#define B_DIM 32
#define C_DIM 256
#define N_DIM 1024
#define NHEAD 8
#define DHEAD 32
#define NWRD 32   // N/32 bit-words per row

// LIF step, exact reference rounding: v += (x-v)/2; s = v>=vth; hard reset.
__device__ __forceinline__ float lif_step(float& v, float x, float vth) {
    v = __fadd_rn(v, __fmul_rn(__fsub_rn(x, v), 0.5f));
    const float s = (v >= vth) ? 1.0f : 0.0f;
    if (s != 0.0f) v = 0.0f;
    return s;
}

// async global->LDS, 16B per lane. LDS dest = wave-uniform base + lane*16.
__device__ __forceinline__ void async_copy16(const float* g, float* l) {
    __builtin_amdgcn_global_load_lds(
        (const __attribute__((address_space(1))) unsigned int*)g,
        (__attribute__((address_space(3))) unsigned int*)l, 16, 0, 0);
}

// Pre-transpose: wqk_t[k][h*64+j] = (j<32 ? qw[h*32+j][k] : kw[h*32+j-32][k])
//                p_t[k][c] = pw[c][k]
__global__ __launch_bounds__(256) void k_transpose(
    const float* __restrict__ qw, const float* __restrict__ kw,
    const float* __restrict__ pw, float* __restrict__ wqk_t,
    float* __restrict__ p_t)
{
    const int i = blockIdx.x * 256 + threadIdx.x;
    if (i < C_DIM * 512) {
        const int k = i >> 9, col = i & 511;
        const int h = col >> 6, j = col & 63;
        wqk_t[i] = (j < 32) ? qw[(size_t)(h * 32 + j) * C_DIM + k]
                            : kw[(size_t)(h * 32 + j - 32) * C_DIM + k];
    } else {
        const int i2 = i - C_DIM * 512;            // < 65536
        const int k = i2 >> 8, c = i2 & 255;
        p_t[i2] = pw[(size_t)c * C_DIM + k];
    }
}

// K1: Q/K GEMM + BN + LIF + head-sum + attn LIF -> bit-packed x_one
// grid (NHEAD, N/64, B), block 256. Tile rows 0..31 = q chans, 32..63 = k chans.
__global__ __launch_bounds__(256) void k_qk(
    const float* __restrict__ x, const float* __restrict__ wqk,   // [256][512] transposed
    const float* __restrict__ qg, const float* __restrict__ qbeta,
    const float* __restrict__ qmean, const float* __restrict__ qvar,
    const float* __restrict__ kg, const float* __restrict__ kbeta,
    const float* __restrict__ kmean, const float* __restrict__ kvar,
    uint32_t* __restrict__ xbits)
{
    __shared__ float w_lds[64 * 64];    // [k][m]
    __shared__ float x_lds[64 * 64];    // [k][n]
    __shared__ float qsum_lds[64];
    __shared__ float attn_lds[64];
    __shared__ uint32_t pack_lds[64];   // [row(0..31)*2 + word(0..1)]

    const int tid = threadIdx.x;
    const int h = blockIdx.x, nt = blockIdx.y, b = blockIdx.z;
    const int n0g = nt * 64;

    const int  mg   = tid >> 4;
    const int  m0   = mg << 2;
    const int  n0   = (tid & 15) << 2;
    const bool is_q = (mg < 8);

    float inv4[4], bias4[4];
    {
        const float* g  = is_q ? qg    : kg;
        const float* be = is_q ? qbeta : kbeta;
        const float* me = is_q ? qmean : kmean;
        const float* va = is_q ? qvar  : kvar;
        const int cb = h * DHEAD + (is_q ? m0 : (m0 - 32));
        #pragma unroll
        for (int i = 0; i < 4; i++) {
            const float iv = __fdiv_rn(g[cb + i], __fsqrt_rn(__fadd_rn(va[cb + i], 1e-5f)));
            inv4[i]  = iv;
            bias4[i] = __fsub_rn(be[cb + i], __fmul_rn(me[cb + i], iv));
        }
    }

    // staging geometry: lane l of wave wid covers tile row rbase+i*4+(l>>4),
    // cols (l&15)*4..+3  ->  LDS byte offset = group_base + l*16 (contiguous)
    const int wid  = tid >> 6, lane = tid & 63;
    const int lr   = lane >> 4;
    const int lc   = (lane & 15) << 2;
    const int rbase = wid * 16;

    float* wl_dst = w_lds + rbase * 64;
    float* xl_dst = x_lds + rbase * 64;
    const float* wg0 = wqk + (size_t)(rbase + lr) * 512 + h * 64 + lc;

    float vstate[16];
    #pragma unroll
    for (int i = 0; i < 16; i++) vstate[i] = 0.0f;
    float v_attn = 0.0f;

    for (int t = 0; t < T_DIM; ++t) {
        float acc[16];
        #pragma unroll
        for (int i = 0; i < 16; i++) acc[i] = 0.0f;

        const float* xg0 = x + ((size_t)(t * B_DIM + b) * C_DIM + rbase + lr) * N_DIM + n0g + lc;

        for (int kk = 0; kk < C_DIM; kk += 64) {
            // issue async stages (prev chunk's readers joined at trailing barrier)
            #pragma unroll
            for (int i = 0; i < 4; i++) {
                async_copy16(wg0 + (size_t)(kk + i * 4) * 512,   wl_dst + i * 256);
                async_copy16(xg0 + (size_t)(kk + i * 4) * N_DIM, xl_dst + i * 256);
            }
            __syncthreads();   // drains vmcnt, joins all waves
            // inner GEMM: strict k-ascending single accumulator chain (bit-stable)
            #pragma unroll 4
            for (int k = 0; k < 64; k++) {
                const float4 a  = *(const float4*)(w_lds + k * 64 + m0);
                const float4 bv = *(const float4*)(x_lds + k * 64 + n0);
                acc[ 0] = fmaf(a.x, bv.x, acc[ 0]);
                acc[ 1] = fmaf(a.x, bv.y, acc[ 1]);
                acc[ 2] = fmaf(a.x, bv.z, acc[ 2]);
                acc[ 3] = fmaf(a.x, bv.w, acc[ 3]);
                acc[ 4] = fmaf(a.y, bv.x, acc[ 4]);
                acc[ 5] = fmaf(a.y, bv.y, acc[ 5]);
                acc[ 6] = fmaf(a.y, bv.z, acc[ 6]);
                acc[ 7] = fmaf(a.y, bv.w, acc[ 7]);
                acc[ 8] = fmaf(a.z, bv.x, acc[ 8]);
                acc[ 9] = fmaf(a.z, bv.y, acc[ 9]);
                acc[10] = fmaf(a.z, bv.z, acc[10]);
                acc[11] = fmaf(a.z, bv.w, acc[11]);
                acc[12] = fmaf(a.w, bv.x, acc[12]);
                acc[13] = fmaf(a.w, bv.y, acc[13]);
                acc[14] = fmaf(a.w, bv.z, acc[14]);
                acc[15] = fmaf(a.w, bv.w, acc[15]);
            }
            __syncthreads();   // readers done before next chunk's stages
        }

        // BN + LIF
        float sarr[16];
        #pragma unroll
        for (int i = 0; i < 4; i++) {
            #pragma unroll
            for (int j = 0; j < 4; j++) {
                const float y = __fadd_rn(__fmul_rn(acc[i * 4 + j], inv4[i]), bias4[i]);
                sarr[i * 4 + j] = lif_step(vstate[i * 4 + j], y, 1.0f);
            }
        }

        if (tid < 64) { qsum_lds[tid] = 0.0f; pack_lds[tid] = 0u; }
        __syncthreads();

        // head-sum of q spikes (integer-valued -> exact in any order)
        if (is_q) {
            #pragma unroll
            for (int j = 0; j < 4; j++) {
                const float cs = sarr[j] + sarr[4 + j] + sarr[8 + j] + sarr[12 + j];
                atomicAdd(&qsum_lds[n0 + j], cs);
            }
        }
        __syncthreads();
        if (tid < 64) attn_lds[tid] = lif_step(v_attn, qsum_lds[tid], 0.5f);
        __syncthreads();

        // x_one = attn * k_spikes, bit-packed: row-local k-chan, 64 bits -> 2 words
        if (!is_q) {
            #pragma unroll
            for (int i = 0; i < 4; i++) {
                uint32_t nib = 0;
                #pragma unroll
                for (int j = 0; j < 4; j++) {
                    if (sarr[i * 4 + j] != 0.0f && attn_lds[n0 + j] != 0.0f)
                        nib |= (1u << j);
                }
                if (nib)
                    atomicOr(&pack_lds[((m0 - 32) + i) * 2 + (n0 >> 5)], nib << (n0 & 31));
            }
        }
        __syncthreads();
        if (tid < 64) {
            const int row = tid >> 1, word = tid & 1;
            const int c = h * DHEAD + row;
            xbits[((size_t)(t * B_DIM + b) * C_DIM + c) * NWRD + (n0g >> 5) + word] = pack_lds[tid];
        }
        // pack_lds/qsum_lds reused next t only after chunk-loop barriers
    }
}

// K2: projection GEMM (bit-packed binary input) + bias + BN + LIF -> spikes
// grid (C/64, N/64, B), block 256.
__global__ __launch_bounds__(256) void k_proj(
    const uint32_t* __restrict__ xbits, const float* __restrict__ pt,  // [256][256] transposed
    const float* __restrict__ pbias, const float* __restrict__ pg,
    const float* __restrict__ pbeta, const float* __restrict__ pmean,
    const float* __restrict__ pvar, float* __restrict__ out)
{
    __shared__ float w_lds[64 * 64];
    __shared__ float x_lds[64 * 64];

    const int tid = threadIdx.x;
    const int mt = blockIdx.x, nt = blockIdx.y, b = blockIdx.z;
    const int n0g = nt * 64;
    const int c0  = mt * 64;

    const int mg = tid >> 4, m0 = mg << 2;
    const int n0 = (tid & 15) << 2;

    float inv4[4], bias4[4], pb4[4];
    #pragma unroll
    for (int i = 0; i < 4; i++) {
        const int c = c0 + m0 + i;
        const float iv = __fdiv_rn(pg[c], __fsqrt_rn(__fadd_rn(pvar[c], 1e-5f)));
        inv4[i]  = iv;
        bias4[i] = __fsub_rn(pbeta[c], __fmul_rn(pmean[c], iv));
        pb4[i]   = pbias[c];
    }

    const int wid = tid >> 6, lane = tid & 63;
    const int lr  = lane >> 4;
    const int lc  = (lane & 15) << 2;
    const int rbase = wid * 16;

    float* wl_dst = w_lds + rbase * 64;
    const float* wg0 = pt + (size_t)(rbase + lr) * 256 + c0 + lc;
    const int wsel = (lane & 15) >> 3;        // which 32-bit word of the 64-col tile
    const int shf  = (lane & 7) * 4;          // bit offset of this lane's 4 cols

    float vstate[16];
    #pragma unroll
    for (int i = 0; i < 16; i++) vstate[i] = 0.0f;

    for (int t = 0; t < T_DIM; ++t) {
        float acc[16];
        #pragma unroll
        for (int i = 0; i < 16; i++) acc[i] = 0.0f;

        const uint32_t* xg0 = xbits + ((size_t)(t * B_DIM + b) * C_DIM + rbase + lr) * NWRD
                              + (n0g >> 5) + wsel;

        for (int kk = 0; kk < C_DIM; kk += 64) {
            #pragma unroll
            for (int i = 0; i < 4; i++)
                async_copy16(wg0 + (size_t)(kk + i * 4) * 256, wl_dst + i * 256);
            // unpack spike bits -> LDS (contiguous lane*16B writes, conflict-free)
            #pragma unroll
            for (int i = 0; i < 4; i++) {
                const uint32_t wv = xg0[(size_t)(kk + i * 4) * NWRD];
                float4 f;
                f.x = ((wv >> (shf + 0)) & 1u) ? 1.0f : 0.0f;
                f.y = ((wv >> (shf + 1)) & 1u) ? 1.0f : 0.0f;
                f.z = ((wv >> (shf + 2)) & 1u) ? 1.0f : 0.0f;
                f.w = ((wv >> (shf + 3)) & 1u) ? 1.0f : 0.0f;
                *(float4*)(x_lds + (rbase + i * 4 + lr) * 64 + lc) = f;
            }
            __syncthreads();
            #pragma unroll 4
            for (int k = 0; k < 64; k++) {
                const float4 a  = *(const float4*)(w_lds + k * 64 + m0);
                const float4 bv = *(const float4*)(x_lds + k * 64 + n0);
                acc[ 0] = fmaf(a.x, bv.x, acc[ 0]);
                acc[ 1] = fmaf(a.x, bv.y, acc[ 1]);
                acc[ 2] = fmaf(a.x, bv.z, acc[ 2]);
                acc[ 3] = fmaf(a.x, bv.w, acc[ 3]);
                acc[ 4] = fmaf(a.y, bv.x, acc[ 4]);
                acc[ 5] = fmaf(a.y, bv.y, acc[ 5]);
                acc[ 6] = fmaf(a.y, bv.z, acc[ 6]);
                acc[ 7] = fmaf(a.y, bv.w, acc[ 7]);
                acc[ 8] = fmaf(a.z, bv.x, acc[ 8]);
                acc[ 9] = fmaf(a.z, bv.y, acc[ 9]);
                acc[10] = fmaf(a.z, bv.z, acc[10]);
                acc[11] = fmaf(a.z, bv.w, acc[11]);
                acc[12] = fmaf(a.w, bv.x, acc[12]);
                acc[13] = fmaf(a.w, bv.y, acc[13]);
                acc[14] = fmaf(a.w, bv.z, acc[14]);
                acc[15] = fmaf(a.w, bv.w, acc[15]);
            }
            __syncthreads();
        }

        #pragma unroll
        for (int i = 0; i < 4; i++) {
            float s4[4];
            #pragma unroll
            for (int j = 0; j < 4; j++) {
                float y = __fadd_rn(acc[i * 4 + j], pb4[i]);
                y = __fadd_rn(__fmul_rn(y, inv4[i]), bias4[i]);
                s4[j] = lif_step(vstate[i * 4 + j], y, 1.0f);
            }
            const int c = c0 + m0 + i;
            float4 o4;
            o4.x = s4[0]; o4.y = s4[1]; o4.z = s4[2]; o4.w = s4[3];
            *(float4*)(out + ((size_t)(t * B_DIM + b) * C_DIM + c) * N_DIM + n0g + n0) = o4;
        }
    }
}

extern "C" void kernel_launch(void* const* d_in, const int* in_sizes, int n_in,
                              void* d_out, int out_size, void* d_ws, size_t ws_size,
                              hipStream_t stream) {
    const float* x    = (const float*)d_in[0];
    const float* q_w  = (const float*)d_in[1];
    const float* q_g  = (const float*)d_in[2];
    const float* q_b  = (const float*)d_in[3];
    const float* q_m  = (const float*)d_in[4];
    const float* q_v  = (const float*)d_in[5];
    const float* k_w  = (const float*)d_in[6];
    const float* k_g  = (const float*)d_in[7];
    const float* k_b  = (const float*)d_in[8];
    const float* k_m  = (const float*)d_in[9];
    const float* k_v  = (const float*)d_in[10];
    const float* p_w  = (const float*)d_in[11];
    const float* p_b  = (const float*)d_in[12];
    const float* p_g  = (const float*)d_in[13];
    const float* p_be = (const float*)d_in[14];
    const float* p_m  = (const float*)d_in[15];
    const float* p_v  = (const float*)d_in[16];

    // ws layout: wqk_t 512KB | p_t 256KB | xbits 4MB   (total ~4.75MB)
    float*    wqk_t = (float*)d_ws;
    float*    p_t   = (float*)((char*)d_ws + 524288);
    uint32_t* xbits = (uint32_t*)((char*)d_ws + 786432);
    float*    out   = (float*)d_out;

    k_transpose<<<768, 256, 0, stream>>>(q_w, k_w, p_w, wqk_t, p_t);

    dim3 g1(NHEAD, N_DIM / 64, B_DIM);
    k_qk<<<g1, 256, 0, stream>>>(x, wqk_t, q_g, q_b, q_m, q_v,
                                 k_g, k_b, k_m, k_v, xbits);

    dim3 g2(C_DIM / 64, N_DIM / 64, B_DIM);
    k_proj<<<g2, 256, 0, stream>>>(xbits, p_t, p_b, p_g, p_be, p_m, p_v, out);
}